// Round 22
// baseline (309.053 us; speedup 1.0000x reference)
//
#include <hip/hip_runtime.h>
#include <hip/hip_bf16.h>

// NonLocalBlock2D: x[8,256,64,64] fp32
// All-fp16 pipeline, batches in QUADS. gemm1 AND gemm2 are LDS-staged
// 128x128-block GEMMs, XOR-swizzled LDS, XCD-aware block swizzle,
// raw v_exp_f32 + cvt_pkrtz epilogue.
//   k_prep_w  : weights -> wAll fp16 [384][256], Wc fp16 [256][128]
//   k_proj    : FUSED transpose+projection (x staged fp16 in LDS, 6 waves)
//   k_gemm1   : K-QUARTER staging (16KB LDS -> high occupancy);
//               E'[bi][n][m] = exp(theta·phi - lmax[rb][m]); lmax/lsum[64][m]
//   k_prep    : cmax/ssum from lmax/lsum; sca[bi][rb][m] fp16; gs fp16 = g*rcp
//   k_gemm2   : 2-deep pipelined: partial[b][kc][n][c] (fp16) = sum_m gs·(E'*sca)
//   k_conv    : out = Wc·(sum_kc partial) + Wb + x  (packed fp16 slice sum)

#define IC   128
#define CIN  256
#define NPOS 4096
#define NB   8

typedef _Float16 f16;
typedef __attribute__((ext_vector_type(8))) _Float16 f16x8;
typedef __attribute__((ext_vector_type(4))) _Float16 f16x4;
typedef __attribute__((ext_vector_type(4))) float f32x4;
typedef __attribute__((ext_vector_type(4))) float fvec4;
typedef __attribute__((ext_vector_type(2))) unsigned int u32x2;

#define MFMA16(a, b, c) __builtin_amdgcn_mfma_f32_16x16x32_f16((a), (b), (c), 0, 0, 0)
#define EXP2(x) __builtin_amdgcn_exp2f(x)

// ---------------- weight prep: wAll fp16 [384][256], Wc fp16 [256][128] ----------------
__global__ __launch_bounds__(256) void k_prep_w(
    const float* __restrict__ gw, const float* __restrict__ tw, const float* __restrict__ pw,
    const float* __restrict__ Ww, f16* __restrict__ wAll, f16* __restrict__ Wc)
{
    const int idx = (blockIdx.x * 256 + threadIdx.x) * 4;
    if (idx < 384 * 256) {
        const int row = idx >> 8, col = idx & 255;
        const float* src = (row < 128) ? (gw + row * 256)
                         : (row < 256) ? (tw + (row - 128) * 256)
                                       : (pw + (row - 256) * 256);
        fvec4 v = *reinterpret_cast<const fvec4*>(src + col);
        f16x4 o = { (f16)v[0], (f16)v[1], (f16)v[2], (f16)v[3] };
        *reinterpret_cast<f16x4*>(wAll + idx) = o;
    } else {
        const int j = idx - 384 * 256;          // over 256*128
        fvec4 v = *reinterpret_cast<const fvec4*>(Ww + j);
        f16x4 o = { (f16)v[0], (f16)v[1], (f16)v[2], (f16)v[3] };
        *reinterpret_cast<f16x4*>(Wc + j) = o;
    }
}

// ---- FUSED transpose + projections: block = 64 n-rows, 6 waves (one per
//      64-output set). x staged fp32->fp16 into swizzled LDS. ----
__global__ __launch_bounds__(384) void k_proj(
    const float* __restrict__ x, const f16* __restrict__ wAll,
    const float* __restrict__ gb, const float* __restrict__ tb, const float* __restrict__ pb,
    f16* __restrict__ th, f16* __restrict__ ph, f16* __restrict__ gT)
{
    __shared__ f16 Xl[64 * 256];   // 32 KB, 16B-chunk XOR swizzle
    const int t  = threadIdx.x;
    const int b  = blockIdx.y;
    const int n0 = blockIdx.x * 64;

    if (t < 256) {
        const int nq = (t & 15) * 4;
        const float* xb = x + (size_t)b * CIN * NPOS + n0 + nq;
#pragma unroll
        for (int it = 0; it < 16; ++it) {
            const int c = (t >> 4) + it * 16;
            fvec4 v = *reinterpret_cast<const fvec4*>(xb + (size_t)c * NPOS);
#pragma unroll
            for (int d = 0; d < 4; ++d) {
                const int row = nq + d;
                const int cs  = (c >> 3) ^ (row & 7);
                Xl[row * 256 + cs * 8 + (c & 7)] = (f16)v[d];
            }
        }
    }
    __syncthreads();

    const int w    = t >> 6;                  // 0..5, set index
    const int lane = t & 63;
    const int lrow = lane & 15;
    const int kg   = lane >> 4;
    const int c0   = w * 64;                  // [0,384)

    f32x4 acc[4][4] = {};
#pragma unroll
    for (int ks = 0; ks < 8; ++ks) {
        const int k = ks * 32 + kg * 8;
        f16x8 a[4], bv[4];
#pragma unroll
        for (int i = 0; i < 4; ++i)
            a[i] = *reinterpret_cast<const f16x8*>(wAll + (size_t)(c0 + i * 16 + lrow) * CIN + k);
#pragma unroll
        for (int j = 0; j < 4; ++j) {
            const int row = j * 16 + lrow;
            const int cs  = (k >> 3) ^ (row & 7);
            bv[j] = *reinterpret_cast<const f16x8*>(&Xl[row * 256 + cs * 8]);
        }
#pragma unroll
        for (int i = 0; i < 4; ++i)
#pragma unroll
            for (int j = 0; j < 4; ++j)
                acc[i][j] = MFMA16(a[i], bv[j], acc[i][j]);
    }
    const int set = c0 >> 7;                 // 0:g 1:theta 2:phi
    if (set == 0) {
#pragma unroll
        for (int i = 0; i < 4; ++i) {
            const int c = c0 + i * 16 + kg * 4;
#pragma unroll
            for (int j = 0; j < 4; ++j) {
                const int n = n0 + j * 16 + lrow;
#pragma unroll
                for (int r = 0; r < 4; ++r)
                    gT[((size_t)b * IC + c + r) * NPOS + n] = (f16)(acc[i][j][r] + gb[c + r]);
            }
        }
    } else {
        const float* Bi = (set == 1) ? tb : pb;
        f16* dst = (set == 1) ? th : ph;
        const int cl0 = (c0 & 127);
#pragma unroll
        for (int i = 0; i < 4; ++i) {
            const int c = cl0 + i * 16 + kg * 4;
#pragma unroll
            for (int j = 0; j < 4; ++j) {
                const int n = n0 + j * 16 + lrow;
                f16x4 o = { (f16)(acc[i][j][0] + Bi[c + 0]), (f16)(acc[i][j][1] + Bi[c + 1]),
                            (f16)(acc[i][j][2] + Bi[c + 2]), (f16)(acc[i][j][3] + Bi[c + 3]) };
                *reinterpret_cast<f16x4*>(dst + ((size_t)b * NPOS + n) * IC + c) = o;
            }
        }
    }
}

// ---- GEMM1 (quad): LDS-staged 128x128 block, K-QUARTER staging (16KB LDS),
//      XCD-swizzled blockIdx, raw-exp2 + cvt_pkrtz epilogue. ----
__global__ __launch_bounds__(256, 4) void k_gemm1(
    const f16* __restrict__ th, const f16* __restrict__ ph,
    f16* __restrict__ Ep, float* __restrict__ lmax, float* __restrict__ lsum, int b0)
{
    __shared__ f16 Alds[128 * 32];    // phi tile, one K-quarter (8 KB)
    __shared__ f16 Blds[128 * 32];    // theta tile, one K-quarter
    const int t    = threadIdx.x;
    const int w    = t >> 6;
    const int lane = t & 63;
    const int lrow = lane & 15;
    const int kg   = lane >> 4;
    const int wm   = w & 1;
    const int wn   = w >> 1;
    // XCD-aware swizzle: 4096 blocks, 8 XCDs, chunk = 512
    const int swz  = (blockIdx.x & 7) * 512 + (blockIdx.x >> 3);
    const int bi   = swz >> 10;               // 0..3
    const int rest = swz & 1023;
    const int mblk = rest & 31;
    const int nblk = rest >> 5;

    const f16* Ag = ph + (size_t)(b0 + bi) * NPOS * IC + (size_t)(mblk * 128) * IC;
    const f16* Bg = th + (size_t)(b0 + bi) * NPOS * IC + (size_t)(nblk * 128) * IC;

    const int trow = t >> 2;                  // 0..63
    const int tc   = t & 3;                   // 16B chunk 0..3

    f32x4 acc[4][4] = {};
#pragma unroll
    for (int q = 0; q < 4; ++q) {             // K quarters of 32
        if (q) __syncthreads();
#pragma unroll
        for (int it = 0; it < 2; ++it) {
            const int row = trow + it * 64;
            const int cs  = tc ^ (row & 3);
            *reinterpret_cast<f16x8*>(&Alds[row * 32 + cs * 8]) =
                *reinterpret_cast<const f16x8*>(Ag + (size_t)row * IC + q * 32 + tc * 8);
            *reinterpret_cast<f16x8*>(&Blds[row * 32 + cs * 8]) =
                *reinterpret_cast<const f16x8*>(Bg + (size_t)row * IC + q * 32 + tc * 8);
        }
        __syncthreads();
        {
            f16x8 a[4], bv[4];
#pragma unroll
            for (int i = 0; i < 4; ++i) {
                const int mr = wm * 64 + i * 16 + lrow;
                const int cs = kg ^ (mr & 3);
                a[i] = *reinterpret_cast<const f16x8*>(&Alds[mr * 32 + cs * 8]);
            }
#pragma unroll
            for (int j = 0; j < 4; ++j) {
                const int nr = wn * 64 + j * 16 + lrow;
                const int cs = kg ^ (nr & 3);
                bv[j] = *reinterpret_cast<const f16x8*>(&Blds[nr * 32 + cs * 8]);
            }
#pragma unroll
            for (int i = 0; i < 4; ++i)
#pragma unroll
                for (int j = 0; j < 4; ++j)
                    acc[i][j] = MFMA16(a[i], bv[j], acc[i][j]);
        }
    }

    const int m0 = mblk * 128 + wm * 64;
    const int n0 = nblk * 128 + wn * 64;
    f16* eb = Ep + (size_t)bi * NPOS * NPOS;
    const float L2E = 1.4426950408889634f;

    // pass A: per-m column max over this wave's 64 n
    f32x4 cm[4], ncml[4];
#pragma unroll
    for (int i = 0; i < 4; ++i)
#pragma unroll
        for (int r = 0; r < 4; ++r) {
            float c = fmaxf(fmaxf(acc[i][0][r], acc[i][1][r]),
                            fmaxf(acc[i][2][r], acc[i][3][r]));
            c = fmaxf(c, __shfl_xor(c, 1));
            c = fmaxf(c, __shfl_xor(c, 2));
            c = fmaxf(c, __shfl_xor(c, 4));
            c = fmaxf(c, __shfl_xor(c, 8));
            cm[i][r] = c;
            ncml[i][r] = -c * L2E;
        }

    // pass B: j-outer / i-inner — line-coalesced stores + running sums
    f32x4 s[4] = {};
#pragma unroll
    for (int j = 0; j < 4; ++j) {
        f16* rowp = eb + (size_t)(n0 + j * 16 + lrow) * NPOS + m0 + kg * 4;
#pragma unroll
        for (int i = 0; i < 4; ++i) {
            float e0 = EXP2(__builtin_fmaf(acc[i][j][0], L2E, ncml[i][0]));
            float e1 = EXP2(__builtin_fmaf(acc[i][j][1], L2E, ncml[i][1]));
            float e2 = EXP2(__builtin_fmaf(acc[i][j][2], L2E, ncml[i][2]));
            float e3 = EXP2(__builtin_fmaf(acc[i][j][3], L2E, ncml[i][3]));
            s[i][0] += e0; s[i][1] += e1; s[i][2] += e2; s[i][3] += e3;
            u32x2 o = { __builtin_bit_cast(unsigned int, __builtin_amdgcn_cvt_pkrtz(e0, e1)),
                        __builtin_bit_cast(unsigned int, __builtin_amdgcn_cvt_pkrtz(e2, e3)) };
            *reinterpret_cast<u32x2*>(rowp + i * 16) = o;
        }
    }

    // stats out (64-row slots)
    const int rowblk = nblk * 2 + wn;         // 0..63
#pragma unroll
    for (int i = 0; i < 4; ++i)
#pragma unroll
        for (int r = 0; r < 4; ++r) {
            float ss = s[i][r];
            ss += __shfl_xor(ss, 1);
            ss += __shfl_xor(ss, 2);
            ss += __shfl_xor(ss, 4);
            ss += __shfl_xor(ss, 8);
            if (lrow == 0) {
                const size_t off = ((size_t)bi * 64 + rowblk) * NPOS + m0 + i * 16 + kg * 4 + r;
                lmax[off] = cm[i][r];
                lsum[off] = ss;
            }
        }
}

// ---- prep (quad): cmax/ssum over 64 slots; sca fp16; gs = g/ssum ----
__global__ __launch_bounds__(256) void k_prep(
    const float* __restrict__ lmax, const float* __restrict__ lsum,
    const f16* __restrict__ gT, f16* __restrict__ sca, f16* __restrict__ gs, int b0)
{
    const float L2E = 1.4426950408889634f;
    const int bi = blockIdx.y;
    const int m  = blockIdx.x * 256 + threadIdx.x;
    const float* lm = lmax + (size_t)bi * 64 * NPOS;
    const float* ls = lsum + (size_t)bi * 64 * NPOS;
    float cm = -3.0e38f;
#pragma unroll 8
    for (int rb = 0; rb < 64; ++rb)
        cm = fmaxf(cm, lm[(size_t)rb * NPOS + m]);
    float s = 0.f;
    f16* scab = sca + (size_t)bi * 64 * NPOS;
#pragma unroll 8
    for (int rb = 0; rb < 64; ++rb) {
        float e = EXP2((lm[(size_t)rb * NPOS + m] - cm) * L2E);
        s += e * ls[(size_t)rb * NPOS + m];
        scab[(size_t)rb * NPOS + m] = (f16)e;
    }
    const float rc = 1.0f / s;
    const f16* gb = gT + (size_t)(b0 + bi) * IC * NPOS;
    f16* gsb = gs + (size_t)bi * IC * NPOS;
#pragma unroll 8
    for (int c = 0; c < IC; ++c)
        gsb[(size_t)c * NPOS + m] = (f16)((float)gb[(size_t)c * NPOS + m] * rc);
}

// ---- GEMM2 (quad): LDS-staged 128c x 128n block, 64-m sub-chunks,
//      2-deep double-buffered pipeline, XCD-swizzled blockIdx.
//      partial[b][kc][n][c] persists across quads. ----
__global__ __launch_bounds__(256, 2) void k_gemm2(
    const f16* __restrict__ Ep, const f16* __restrict__ sca,
    const f16* __restrict__ gs, f16* __restrict__ partial, int b0)
{
    __shared__ f16 Elds[2][128 * 64];   // E' tile (n rows), double-buffered
    __shared__ f16 Glds[2][128 * 64];   // gs tile (c rows)
    const int t    = threadIdx.x;
    const int w    = t >> 6;
    const int lane = t & 63;
    const int lrow = lane & 15;
    const int kg   = lane >> 4;
    const int wc   = w & 1;
    const int wn   = w >> 1;
    // XCD-aware swizzle: 512 blocks, 8 XCDs, chunk = 64
    const int swz  = (blockIdx.x & 7) * 64 + (blockIdx.x >> 3);
    const int bi   = swz >> 7;                // 0..3
    const int rest = swz & 127;
    const int kc   = rest & 3;                // m-chunk of 1024
    const int nblk = rest >> 2;               // 0..31, n-block of 128

    const f16* Eg  = Ep + (size_t)bi * NPOS * NPOS + (size_t)(nblk * 128) * NPOS + kc * 1024;
    const f16* Gg  = gs + (size_t)bi * IC * NPOS + kc * 1024;
    const int  rb  = nblk * 2 + wn;           // wave's 64-row stats slot
    const f16* srow = sca + ((size_t)bi * 64 + rb) * NPOS + kc * 1024;

    const int trow = t >> 3;                  // 0..31
    const int tc   = t & 7;                   // 16B chunk 0..7

    // prefetch sub-chunk 0
    f16x8 pe[4], pg[4];
#pragma unroll
    for (int it = 0; it < 4; ++it) {
        const int row = trow + it * 32;
        pe[it] = *reinterpret_cast<const f16x8*>(Eg + (size_t)row * NPOS + tc * 8);
        pg[it] = *reinterpret_cast<const f16x8*>(Gg + (size_t)row * NPOS + tc * 8);
    }

    f32x4 acc[4][4] = {};
    for (int sc = 0; sc < 16; ++sc) {         // 16 sub-chunks of 64 m
        const int cur = sc & 1;
        // write staged regs to LDS (swizzled)
#pragma unroll
        for (int it = 0; it < 4; ++it) {
            const int row = trow + it * 32;
            const int cs  = tc ^ (row & 7);
            *reinterpret_cast<f16x8*>(&Elds[cur][row * 64 + cs * 8]) = pe[it];
            *reinterpret_cast<f16x8*>(&Glds[cur][row * 64 + cs * 8]) = pg[it];
        }
        // issue next sub-chunk's loads — in flight across barrier + MFMA
        if (sc < 15) {
#pragma unroll
            for (int it = 0; it < 4; ++it) {
                const int row = trow + it * 32;
                pe[it] = *reinterpret_cast<const f16x8*>(Eg + (size_t)row * NPOS + (sc + 1) * 64 + tc * 8);
                pg[it] = *reinterpret_cast<const f16x8*>(Gg + (size_t)row * NPOS + (sc + 1) * 64 + tc * 8);
            }
        }
        __syncthreads();

#pragma unroll
        for (int ks = 0; ks < 2; ++ks) {
            f16x8 sv = *reinterpret_cast<const f16x8*>(srow + sc * 64 + ks * 32 + kg * 8);
            f16x8 a[4], ev[4];
#pragma unroll
            for (int i = 0; i < 4; ++i) {
                const int cr = wc * 64 + i * 16 + lrow;
                const int cs = (ks * 4 + kg) ^ (cr & 7);
                a[i] = *reinterpret_cast<const f16x8*>(&Glds[cur][cr * 64 + cs * 8]);
            }
#pragma unroll
            for (int j = 0; j < 4; ++j) {
                const int nr = wn * 64 + j * 16 + lrow;
                const int cs = (ks * 4 + kg) ^ (nr & 7);
                ev[j] = *reinterpret_cast<const f16x8*>(&Elds[cur][nr * 64 + cs * 8]) * sv;
            }
#pragma unroll
            for (int i = 0; i < 4; ++i)
#pragma unroll
                for (int j = 0; j < 4; ++j)
                    acc[i][j] = MFMA16(a[i], ev[j], acc[i][j]);
        }
        // no trailing barrier: next iter writes buf[cur^1]; buf[cur] is only
        // rewritten at sc+2, separated from this iter's reads by sc+1's barrier
    }

    // store partial: n rows, c cols; j-outer/i-inner for contiguous 64B runs
    f16* pb = partial + ((size_t)(b0 + bi) * 4 + kc) * NPOS * IC;
    const int n0 = nblk * 128 + wn * 64;
    const int c0 = wc * 64;
#pragma unroll
    for (int j = 0; j < 4; ++j) {
        f16* rowp = pb + (size_t)(n0 + j * 16 + lrow) * IC + c0 + kg * 4;
#pragma unroll
        for (int i = 0; i < 4; ++i) {
            f16x4 o = { (f16)acc[i][j][0], (f16)acc[i][j][1],
                        (f16)acc[i][j][2], (f16)acc[i][j][3] };
            *reinterpret_cast<f16x4*>(rowp + i * 16) = o;
        }
    }
}

// ---- final conv + residual: 64x64 per wave; B fragment = packed fp16 sum
//      of the 4 kc partial slices (fixed order, deterministic). ----
__global__ __launch_bounds__(256) void k_conv(
    const float* __restrict__ x, const f16* __restrict__ Wc, const float* __restrict__ Wb,
    const f16* __restrict__ partial, float* __restrict__ out)
{
    const int w    = threadIdx.x >> 6;
    const int lane = threadIdx.x & 63;
    const int lrow = lane & 15;
    const int kg   = lane >> 4;
    const int gwid = blockIdx.x * 4 + w;      // 0..2047
    const int ob   = gwid & 3;                // o-block of 64
    const int nb   = (gwid >> 2) & 63;        // n-block of 64
    const int b    = gwid >> 8;
    const int o0   = ob * 64;
    const int n0   = nb * 64;

    const f16* Y = partial + (size_t)b * 4 * NPOS * IC;   // 4 kc slices
    const size_t SL = (size_t)NPOS * IC;
    f32x4 acc[4][4] = {};
#pragma unroll
    for (int ks = 0; ks < 4; ++ks) {
        const int k = ks * 32 + kg * 8;
        f16x8 a[4], bv[4];
#pragma unroll
        for (int i = 0; i < 4; ++i) {
            a[i]  = *reinterpret_cast<const f16x8*>(Wc + (size_t)(o0 + i * 16 + lrow) * IC + k);
            const f16* yr = Y + (size_t)(n0 + i * 16 + lrow) * IC + k;
            f16x8 v0 = *reinterpret_cast<const f16x8*>(yr);
            f16x8 v1 = *reinterpret_cast<const f16x8*>(yr + SL);
            f16x8 v2 = *reinterpret_cast<const f16x8*>(yr + 2 * SL);
            f16x8 v3 = *reinterpret_cast<const f16x8*>(yr + 3 * SL);
            bv[i] = (v0 + v1) + (v2 + v3);
        }
#pragma unroll
        for (int i = 0; i < 4; ++i)
#pragma unroll
            for (int j = 0; j < 4; ++j)
                acc[i][j] = MFMA16(a[i], bv[j], acc[i][j]);
    }
#pragma unroll
    for (int i = 0; i < 4; ++i) {
        const int o = o0 + i * 16 + kg * 4;
#pragma unroll
        for (int j = 0; j < 4; ++j) {
            const int n = n0 + j * 16 + lrow;
#pragma unroll
            for (int r = 0; r < 4; ++r) {
                const size_t off = ((size_t)b * CIN + o + r) * NPOS + n;
                out[off] = acc[i][j][r] + x[off] + Wb[o + r];
            }
        }
    }
}

extern "C" void kernel_launch(void* const* d_in, const int* in_sizes, int n_in,
                              void* d_out, int out_size, void* d_ws, size_t ws_size,
                              hipStream_t stream)
{
    const float* x  = (const float*)d_in[0];
    const float* gw = (const float*)d_in[1];
    const float* gb = (const float*)d_in[2];
    const float* tw = (const float*)d_in[3];
    const float* tb = (const float*)d_in[4];
    const float* pw = (const float*)d_in[5];
    const float* pb = (const float*)d_in[6];
    const float* Ww = (const float*)d_in[7];
    const float* Wb = (const float*)d_in[8];
    float* out = (float*)d_out;

    char* ws = (char*)d_ws;
    size_t off = 0;
    auto alloc = [&](size_t bytes) -> char* {
        char* p = ws + off;
        off += (bytes + 255) & ~(size_t)255;
        return p;
    };
    f16* wAll = (f16*)alloc((size_t)384 * 256 * 2);
    f16* Wc   = (f16*)alloc((size_t)CIN * IC * 2);
    f16* th   = (f16*)alloc((size_t)NB * NPOS * IC * 2);         // 8.4 MB
    f16* ph   = (f16*)alloc((size_t)NB * NPOS * IC * 2);
    f16* gT   = (f16*)alloc((size_t)NB * NPOS * IC * 2);
    f16* Ep   = (f16*)alloc((size_t)4 * NPOS * NPOS * 2);        // 134 MB (quad)
    float* lmax = (float*)alloc((size_t)4 * 64 * NPOS * 4);      // 4.2 MB
    float* lsum = (float*)alloc((size_t)4 * 64 * NPOS * 4);
    f16* sca  = (f16*)alloc((size_t)4 * 64 * NPOS * 2);          // 2.1 MB
    f16* gs   = (f16*)alloc((size_t)4 * IC * NPOS * 2);          // 4.2 MB
    f16* partial = (f16*)alloc((size_t)NB * 4 * NPOS * IC * 2);  // 33.6 MB (persistent)

    k_prep_w<<<128, 256, 0, stream>>>(gw, tw, pw, Ww, wAll, Wc);
    k_proj<<<dim3(64, 8), 384, 0, stream>>>(x, wAll, gb, tb, pb, th, ph, gT);

    for (int b0 = 0; b0 < NB; b0 += 4) {
        k_gemm1<<<4096, 256, 0, stream>>>(th, ph, Ep, lmax, lsum, b0);
        k_prep<<<dim3(16, 4), 256, 0, stream>>>(lmax, lsum, gT, sca, gs, b0);
        k_gemm2<<<512, 256, 0, stream>>>(Ep, sca, gs, partial, b0);
    }
    k_conv<<<dim3(512), 256, 0, stream>>>(x, Wc, Wb, partial, out);
}

// Round 23
// 307.609 us; speedup vs baseline: 1.0047x; 1.0047x over previous
//
#include <hip/hip_runtime.h>
#include <hip/hip_bf16.h>

// NonLocalBlock2D: x[8,256,64,64] fp32
// All-fp16 pipeline, batches in QUADS. gemm1 AND gemm2 are LDS-staged
// 128x128-block GEMMs, XOR-swizzled LDS, XCD-aware block swizzle,
// raw v_exp_f32 + cvt_pkrtz epilogue.
//   k_prep_w  : weights -> wAll fp16 [384][256], Wc fp16 [256][128]
//   k_proj    : FUSED transpose+projection (x staged fp16 in LDS, 6 waves)
//   k_gemm1   : K-half staging (32KB LDS); E' = exp(theta·phi - lmax[rb][m])
//   k_prep    : cmax/ssum from lmax/lsum; sca[bi][rb][m] fp16; gs fp16 = g*rcp
//   k_gemm2   : 2-deep pipelined: partial[b][kc][n][c] (fp16) = sum_m gs·(E'*sca)
//   k_conv    : out = Wc·(sum_kc partial) + Wb + x  (packed fp16 slice sum)

#define IC   128
#define CIN  256
#define NPOS 4096
#define NB   8

typedef _Float16 f16;
typedef __attribute__((ext_vector_type(8))) _Float16 f16x8;
typedef __attribute__((ext_vector_type(4))) _Float16 f16x4;
typedef __attribute__((ext_vector_type(4))) float f32x4;
typedef __attribute__((ext_vector_type(4))) float fvec4;
typedef __attribute__((ext_vector_type(2))) unsigned int u32x2;

#define MFMA16(a, b, c) __builtin_amdgcn_mfma_f32_16x16x32_f16((a), (b), (c), 0, 0, 0)
#define EXP2(x) __builtin_amdgcn_exp2f(x)

// ---------------- weight prep: wAll fp16 [384][256], Wc fp16 [256][128] ----------------
__global__ __launch_bounds__(256) void k_prep_w(
    const float* __restrict__ gw, const float* __restrict__ tw, const float* __restrict__ pw,
    const float* __restrict__ Ww, f16* __restrict__ wAll, f16* __restrict__ Wc)
{
    const int idx = (blockIdx.x * 256 + threadIdx.x) * 4;
    if (idx < 384 * 256) {
        const int row = idx >> 8, col = idx & 255;
        const float* src = (row < 128) ? (gw + row * 256)
                         : (row < 256) ? (tw + (row - 128) * 256)
                                       : (pw + (row - 256) * 256);
        fvec4 v = *reinterpret_cast<const fvec4*>(src + col);
        f16x4 o = { (f16)v[0], (f16)v[1], (f16)v[2], (f16)v[3] };
        *reinterpret_cast<f16x4*>(wAll + idx) = o;
    } else {
        const int j = idx - 384 * 256;          // over 256*128
        fvec4 v = *reinterpret_cast<const fvec4*>(Ww + j);
        f16x4 o = { (f16)v[0], (f16)v[1], (f16)v[2], (f16)v[3] };
        *reinterpret_cast<f16x4*>(Wc + j) = o;
    }
}

// ---- FUSED transpose + projections: block = 64 n-rows, 6 waves (one per
//      64-output set). x staged fp32->fp16 into swizzled LDS. ----
__global__ __launch_bounds__(384) void k_proj(
    const float* __restrict__ x, const f16* __restrict__ wAll,
    const float* __restrict__ gb, const float* __restrict__ tb, const float* __restrict__ pb,
    f16* __restrict__ th, f16* __restrict__ ph, f16* __restrict__ gT)
{
    __shared__ f16 Xl[64 * 256];   // 32 KB, 16B-chunk XOR swizzle
    const int t  = threadIdx.x;
    const int b  = blockIdx.y;
    const int n0 = blockIdx.x * 64;

    if (t < 256) {
        const int nq = (t & 15) * 4;
        const float* xb = x + (size_t)b * CIN * NPOS + n0 + nq;
#pragma unroll
        for (int it = 0; it < 16; ++it) {
            const int c = (t >> 4) + it * 16;
            fvec4 v = *reinterpret_cast<const fvec4*>(xb + (size_t)c * NPOS);
#pragma unroll
            for (int d = 0; d < 4; ++d) {
                const int row = nq + d;
                const int cs  = (c >> 3) ^ (row & 7);
                Xl[row * 256 + cs * 8 + (c & 7)] = (f16)v[d];
            }
        }
    }
    __syncthreads();

    const int w    = t >> 6;                  // 0..5, set index
    const int lane = t & 63;
    const int lrow = lane & 15;
    const int kg   = lane >> 4;
    const int c0   = w * 64;                  // [0,384)

    f32x4 acc[4][4] = {};
#pragma unroll
    for (int ks = 0; ks < 8; ++ks) {
        const int k = ks * 32 + kg * 8;
        f16x8 a[4], bv[4];
#pragma unroll
        for (int i = 0; i < 4; ++i)
            a[i] = *reinterpret_cast<const f16x8*>(wAll + (size_t)(c0 + i * 16 + lrow) * CIN + k);
#pragma unroll
        for (int j = 0; j < 4; ++j) {
            const int row = j * 16 + lrow;
            const int cs  = (k >> 3) ^ (row & 7);
            bv[j] = *reinterpret_cast<const f16x8*>(&Xl[row * 256 + cs * 8]);
        }
#pragma unroll
        for (int i = 0; i < 4; ++i)
#pragma unroll
            for (int j = 0; j < 4; ++j)
                acc[i][j] = MFMA16(a[i], bv[j], acc[i][j]);
    }
    const int set = c0 >> 7;                 // 0:g 1:theta 2:phi
    if (set == 0) {
#pragma unroll
        for (int i = 0; i < 4; ++i) {
            const int c = c0 + i * 16 + kg * 4;
#pragma unroll
            for (int j = 0; j < 4; ++j) {
                const int n = n0 + j * 16 + lrow;
#pragma unroll
                for (int r = 0; r < 4; ++r)
                    gT[((size_t)b * IC + c + r) * NPOS + n] = (f16)(acc[i][j][r] + gb[c + r]);
            }
        }
    } else {
        const float* Bi = (set == 1) ? tb : pb;
        f16* dst = (set == 1) ? th : ph;
        const int cl0 = (c0 & 127);
#pragma unroll
        for (int i = 0; i < 4; ++i) {
            const int c = cl0 + i * 16 + kg * 4;
#pragma unroll
            for (int j = 0; j < 4; ++j) {
                const int n = n0 + j * 16 + lrow;
                f16x4 o = { (f16)(acc[i][j][0] + Bi[c + 0]), (f16)(acc[i][j][1] + Bi[c + 1]),
                            (f16)(acc[i][j][2] + Bi[c + 2]), (f16)(acc[i][j][3] + Bi[c + 3]) };
                *reinterpret_cast<f16x4*>(dst + ((size_t)b * NPOS + n) * IC + c) = o;
            }
        }
    }
}

// ---- GEMM1 (quad): LDS-staged 128x128 block, K-split halves (32KB LDS),
//      XCD-swizzled blockIdx, raw-exp2 + cvt_pkrtz epilogue. ----
__global__ __launch_bounds__(256, 4) void k_gemm1(
    const f16* __restrict__ th, const f16* __restrict__ ph,
    f16* __restrict__ Ep, float* __restrict__ lmax, float* __restrict__ lsum, int b0)
{
    __shared__ f16 Alds[128 * 64];    // phi tile, one K-half
    __shared__ f16 Blds[128 * 64];    // theta tile, one K-half
    const int t    = threadIdx.x;
    const int w    = t >> 6;
    const int lane = t & 63;
    const int lrow = lane & 15;
    const int kg   = lane >> 4;
    const int wm   = w & 1;
    const int wn   = w >> 1;
    // XCD-aware swizzle: 4096 blocks, 8 XCDs, chunk = 512
    const int swz  = (blockIdx.x & 7) * 512 + (blockIdx.x >> 3);
    const int bi   = swz >> 10;               // 0..3
    const int rest = swz & 1023;
    const int mblk = rest & 31;
    const int nblk = rest >> 5;

    const f16* Ag = ph + (size_t)(b0 + bi) * NPOS * IC + (size_t)(mblk * 128) * IC;
    const f16* Bg = th + (size_t)(b0 + bi) * NPOS * IC + (size_t)(nblk * 128) * IC;

    const int trow = t >> 3;                  // 0..31
    const int tc   = t & 7;                   // 16B chunk 0..7

    f32x4 acc[4][4] = {};
#pragma unroll
    for (int h = 0; h < 2; ++h) {             // K halves of 64
        if (h) __syncthreads();
#pragma unroll
        for (int it = 0; it < 4; ++it) {
            const int row = trow + it * 32;
            const int cs  = tc ^ (row & 7);
            *reinterpret_cast<f16x8*>(&Alds[row * 64 + cs * 8]) =
                *reinterpret_cast<const f16x8*>(Ag + (size_t)row * IC + h * 64 + tc * 8);
            *reinterpret_cast<f16x8*>(&Blds[row * 64 + cs * 8]) =
                *reinterpret_cast<const f16x8*>(Bg + (size_t)row * IC + h * 64 + tc * 8);
        }
        __syncthreads();
#pragma unroll
        for (int ks = 0; ks < 2; ++ks) {
            f16x8 a[4], bv[4];
#pragma unroll
            for (int i = 0; i < 4; ++i) {
                const int mr = wm * 64 + i * 16 + lrow;
                const int cs = (ks * 4 + kg) ^ (mr & 7);
                a[i] = *reinterpret_cast<const f16x8*>(&Alds[mr * 64 + cs * 8]);
            }
#pragma unroll
            for (int j = 0; j < 4; ++j) {
                const int nr = wn * 64 + j * 16 + lrow;
                const int cs = (ks * 4 + kg) ^ (nr & 7);
                bv[j] = *reinterpret_cast<const f16x8*>(&Blds[nr * 64 + cs * 8]);
            }
#pragma unroll
            for (int i = 0; i < 4; ++i)
#pragma unroll
                for (int j = 0; j < 4; ++j)
                    acc[i][j] = MFMA16(a[i], bv[j], acc[i][j]);
        }
    }

    const int m0 = mblk * 128 + wm * 64;
    const int n0 = nblk * 128 + wn * 64;
    f16* eb = Ep + (size_t)bi * NPOS * NPOS;
    const float L2E = 1.4426950408889634f;

    // pass A: per-m column max over this wave's 64 n
    f32x4 cm[4], ncml[4];
#pragma unroll
    for (int i = 0; i < 4; ++i)
#pragma unroll
        for (int r = 0; r < 4; ++r) {
            float c = fmaxf(fmaxf(acc[i][0][r], acc[i][1][r]),
                            fmaxf(acc[i][2][r], acc[i][3][r]));
            c = fmaxf(c, __shfl_xor(c, 1));
            c = fmaxf(c, __shfl_xor(c, 2));
            c = fmaxf(c, __shfl_xor(c, 4));
            c = fmaxf(c, __shfl_xor(c, 8));
            cm[i][r] = c;
            ncml[i][r] = -c * L2E;
        }

    // pass B: j-outer / i-inner — line-coalesced stores + running sums
    f32x4 s[4] = {};
#pragma unroll
    for (int j = 0; j < 4; ++j) {
        f16* rowp = eb + (size_t)(n0 + j * 16 + lrow) * NPOS + m0 + kg * 4;
#pragma unroll
        for (int i = 0; i < 4; ++i) {
            float e0 = EXP2(__builtin_fmaf(acc[i][j][0], L2E, ncml[i][0]));
            float e1 = EXP2(__builtin_fmaf(acc[i][j][1], L2E, ncml[i][1]));
            float e2 = EXP2(__builtin_fmaf(acc[i][j][2], L2E, ncml[i][2]));
            float e3 = EXP2(__builtin_fmaf(acc[i][j][3], L2E, ncml[i][3]));
            s[i][0] += e0; s[i][1] += e1; s[i][2] += e2; s[i][3] += e3;
            u32x2 o = { __builtin_bit_cast(unsigned int, __builtin_amdgcn_cvt_pkrtz(e0, e1)),
                        __builtin_bit_cast(unsigned int, __builtin_amdgcn_cvt_pkrtz(e2, e3)) };
            *reinterpret_cast<u32x2*>(rowp + i * 16) = o;
        }
    }

    // stats out (64-row slots)
    const int rowblk = nblk * 2 + wn;         // 0..63
#pragma unroll
    for (int i = 0; i < 4; ++i)
#pragma unroll
        for (int r = 0; r < 4; ++r) {
            float ss = s[i][r];
            ss += __shfl_xor(ss, 1);
            ss += __shfl_xor(ss, 2);
            ss += __shfl_xor(ss, 4);
            ss += __shfl_xor(ss, 8);
            if (lrow == 0) {
                const size_t off = ((size_t)bi * 64 + rowblk) * NPOS + m0 + i * 16 + kg * 4 + r;
                lmax[off] = cm[i][r];
                lsum[off] = ss;
            }
        }
}

// ---- prep (quad): cmax/ssum over 64 slots; sca fp16; gs = g/ssum ----
__global__ __launch_bounds__(256) void k_prep(
    const float* __restrict__ lmax, const float* __restrict__ lsum,
    const f16* __restrict__ gT, f16* __restrict__ sca, f16* __restrict__ gs, int b0)
{
    const float L2E = 1.4426950408889634f;
    const int bi = blockIdx.y;
    const int m  = blockIdx.x * 256 + threadIdx.x;
    const float* lm = lmax + (size_t)bi * 64 * NPOS;
    const float* ls = lsum + (size_t)bi * 64 * NPOS;
    float cm = -3.0e38f;
#pragma unroll 8
    for (int rb = 0; rb < 64; ++rb)
        cm = fmaxf(cm, lm[(size_t)rb * NPOS + m]);
    float s = 0.f;
    f16* scab = sca + (size_t)bi * 64 * NPOS;
#pragma unroll 8
    for (int rb = 0; rb < 64; ++rb) {
        float e = EXP2((lm[(size_t)rb * NPOS + m] - cm) * L2E);
        s += e * ls[(size_t)rb * NPOS + m];
        scab[(size_t)rb * NPOS + m] = (f16)e;
    }
    const float rc = 1.0f / s;
    const f16* gb = gT + (size_t)(b0 + bi) * IC * NPOS;
    f16* gsb = gs + (size_t)bi * IC * NPOS;
#pragma unroll 8
    for (int c = 0; c < IC; ++c)
        gsb[(size_t)c * NPOS + m] = (f16)((float)gb[(size_t)c * NPOS + m] * rc);
}

// ---- GEMM2 (quad): LDS-staged 128c x 128n block, 64-m sub-chunks,
//      2-deep double-buffered pipeline, XCD-swizzled blockIdx.
//      partial[b][kc][n][c] persists across quads. ----
__global__ __launch_bounds__(256, 2) void k_gemm2(
    const f16* __restrict__ Ep, const f16* __restrict__ sca,
    const f16* __restrict__ gs, f16* __restrict__ partial, int b0)
{
    __shared__ f16 Elds[2][128 * 64];   // E' tile (n rows), double-buffered
    __shared__ f16 Glds[2][128 * 64];   // gs tile (c rows)
    const int t    = threadIdx.x;
    const int w    = t >> 6;
    const int lane = t & 63;
    const int lrow = lane & 15;
    const int kg   = lane >> 4;
    const int wc   = w & 1;
    const int wn   = w >> 1;
    // XCD-aware swizzle: 512 blocks, 8 XCDs, chunk = 64
    const int swz  = (blockIdx.x & 7) * 64 + (blockIdx.x >> 3);
    const int bi   = swz >> 7;                // 0..3
    const int rest = swz & 127;
    const int kc   = rest & 3;                // m-chunk of 1024
    const int nblk = rest >> 2;               // 0..31, n-block of 128

    const f16* Eg  = Ep + (size_t)bi * NPOS * NPOS + (size_t)(nblk * 128) * NPOS + kc * 1024;
    const f16* Gg  = gs + (size_t)bi * IC * NPOS + kc * 1024;
    const int  rb  = nblk * 2 + wn;           // wave's 64-row stats slot
    const f16* srow = sca + ((size_t)bi * 64 + rb) * NPOS + kc * 1024;

    const int trow = t >> 3;                  // 0..31
    const int tc   = t & 7;                   // 16B chunk 0..7

    // prefetch sub-chunk 0
    f16x8 pe[4], pg[4];
#pragma unroll
    for (int it = 0; it < 4; ++it) {
        const int row = trow + it * 32;
        pe[it] = *reinterpret_cast<const f16x8*>(Eg + (size_t)row * NPOS + tc * 8);
        pg[it] = *reinterpret_cast<const f16x8*>(Gg + (size_t)row * NPOS + tc * 8);
    }

    f32x4 acc[4][4] = {};
    for (int sc = 0; sc < 16; ++sc) {         // 16 sub-chunks of 64 m
        const int cur = sc & 1;
        // write staged regs to LDS (swizzled)
#pragma unroll
        for (int it = 0; it < 4; ++it) {
            const int row = trow + it * 32;
            const int cs  = tc ^ (row & 7);
            *reinterpret_cast<f16x8*>(&Elds[cur][row * 64 + cs * 8]) = pe[it];
            *reinterpret_cast<f16x8*>(&Glds[cur][row * 64 + cs * 8]) = pg[it];
        }
        // issue next sub-chunk's loads — in flight across barrier + MFMA
        if (sc < 15) {
#pragma unroll
            for (int it = 0; it < 4; ++it) {
                const int row = trow + it * 32;
                pe[it] = *reinterpret_cast<const f16x8*>(Eg + (size_t)row * NPOS + (sc + 1) * 64 + tc * 8);
                pg[it] = *reinterpret_cast<const f16x8*>(Gg + (size_t)row * NPOS + (sc + 1) * 64 + tc * 8);
            }
        }
        __syncthreads();

#pragma unroll
        for (int ks = 0; ks < 2; ++ks) {
            f16x8 sv = *reinterpret_cast<const f16x8*>(srow + sc * 64 + ks * 32 + kg * 8);
            f16x8 a[4], ev[4];
#pragma unroll
            for (int i = 0; i < 4; ++i) {
                const int cr = wc * 64 + i * 16 + lrow;
                const int cs = (ks * 4 + kg) ^ (cr & 7);
                a[i] = *reinterpret_cast<const f16x8*>(&Glds[cur][cr * 64 + cs * 8]);
            }
#pragma unroll
            for (int j = 0; j < 4; ++j) {
                const int nr = wn * 64 + j * 16 + lrow;
                const int cs = (ks * 4 + kg) ^ (nr & 7);
                ev[j] = *reinterpret_cast<const f16x8*>(&Elds[cur][nr * 64 + cs * 8]) * sv;
            }
#pragma unroll
            for (int i = 0; i < 4; ++i)
#pragma unroll
                for (int j = 0; j < 4; ++j)
                    acc[i][j] = MFMA16(a[i], ev[j], acc[i][j]);
        }
        // no trailing barrier: next iter writes buf[cur^1]; buf[cur] is only
        // rewritten at sc+2, separated from this iter's reads by sc+1's barrier
    }

    // store partial: n rows, c cols; j-outer/i-inner for contiguous 64B runs
    f16* pb = partial + ((size_t)(b0 + bi) * 4 + kc) * NPOS * IC;
    const int n0 = nblk * 128 + wn * 64;
    const int c0 = wc * 64;
#pragma unroll
    for (int j = 0; j < 4; ++j) {
        f16* rowp = pb + (size_t)(n0 + j * 16 + lrow) * IC + c0 + kg * 4;
#pragma unroll
        for (int i = 0; i < 4; ++i) {
            f16x4 o = { (f16)acc[i][j][0], (f16)acc[i][j][1],
                        (f16)acc[i][j][2], (f16)acc[i][j][3] };
            *reinterpret_cast<f16x4*>(rowp + i * 16) = o;
        }
    }
}

// ---- final conv + residual: 64x64 per wave; B fragment = packed fp16 sum
//      of the 4 kc partial slices (fixed order, deterministic). ----
__global__ __launch_bounds__(256) void k_conv(
    const float* __restrict__ x, const f16* __restrict__ Wc, const float* __restrict__ Wb,
    const f16* __restrict__ partial, float* __restrict__ out)
{
    const int w    = threadIdx.x >> 6;
    const int lane = threadIdx.x & 63;
    const int lrow = lane & 15;
    const int kg   = lane >> 4;
    const int gwid = blockIdx.x * 4 + w;      // 0..2047
    const int ob   = gwid & 3;                // o-block of 64
    const int nb   = (gwid >> 2) & 63;        // n-block of 64
    const int b    = gwid >> 8;
    const int o0   = ob * 64;
    const int n0   = nb * 64;

    const f16* Y = partial + (size_t)b * 4 * NPOS * IC;   // 4 kc slices
    const size_t SL = (size_t)NPOS * IC;
    f32x4 acc[4][4] = {};
#pragma unroll
    for (int ks = 0; ks < 4; ++ks) {
        const int k = ks * 32 + kg * 8;
        f16x8 a[4], bv[4];
#pragma unroll
        for (int i = 0; i < 4; ++i) {
            a[i]  = *reinterpret_cast<const f16x8*>(Wc + (size_t)(o0 + i * 16 + lrow) * IC + k);
            const f16* yr = Y + (size_t)(n0 + i * 16 + lrow) * IC + k;
            f16x8 v0 = *reinterpret_cast<const f16x8*>(yr);
            f16x8 v1 = *reinterpret_cast<const f16x8*>(yr + SL);
            f16x8 v2 = *reinterpret_cast<const f16x8*>(yr + 2 * SL);
            f16x8 v3 = *reinterpret_cast<const f16x8*>(yr + 3 * SL);
            bv[i] = (v0 + v1) + (v2 + v3);
        }
#pragma unroll
        for (int i = 0; i < 4; ++i)
#pragma unroll
            for (int j = 0; j < 4; ++j)
                acc[i][j] = MFMA16(a[i], bv[j], acc[i][j]);
    }
#pragma unroll
    for (int i = 0; i < 4; ++i) {
        const int o = o0 + i * 16 + kg * 4;
#pragma unroll
        for (int j = 0; j < 4; ++j) {
            const int n = n0 + j * 16 + lrow;
#pragma unroll
            for (int r = 0; r < 4; ++r) {
                const size_t off = ((size_t)b * CIN + o + r) * NPOS + n;
                out[off] = acc[i][j][r] + x[off] + Wb[o + r];
            }
        }
    }
}

extern "C" void kernel_launch(void* const* d_in, const int* in_sizes, int n_in,
                              void* d_out, int out_size, void* d_ws, size_t ws_size,
                              hipStream_t stream)
{
    const float* x  = (const float*)d_in[0];
    const float* gw = (const float*)d_in[1];
    const float* gb = (const float*)d_in[2];
    const float* tw = (const float*)d_in[3];
    const float* tb = (const float*)d_in[4];
    const float* pw = (const float*)d_in[5];
    const float* pb = (const float*)d_in[6];
    const float* Ww = (const float*)d_in[7];
    const float* Wb = (const float*)d_in[8];
    float* out = (float*)d_out;

    char* ws = (char*)d_ws;
    size_t off = 0;
    auto alloc = [&](size_t bytes) -> char* {
        char* p = ws + off;
        off += (bytes + 255) & ~(size_t)255;
        return p;
    };
    f16* wAll = (f16*)alloc((size_t)384 * 256 * 2);
    f16* Wc   = (f16*)alloc((size_t)CIN * IC * 2);
    f16* th   = (f16*)alloc((size_t)NB * NPOS * IC * 2);         // 8.4 MB
    f16* ph   = (f16*)alloc((size_t)NB * NPOS * IC * 2);
    f16* gT   = (f16*)alloc((size_t)NB * NPOS * IC * 2);
    f16* Ep   = (f16*)alloc((size_t)4 * NPOS * NPOS * 2);        // 134 MB (quad)
    float* lmax = (float*)alloc((size_t)4 * 64 * NPOS * 4);      // 4.2 MB
    float* lsum = (float*)alloc((size_t)4 * 64 * NPOS * 4);
    f16* sca  = (f16*)alloc((size_t)4 * 64 * NPOS * 2);          // 2.1 MB
    f16* gs   = (f16*)alloc((size_t)4 * IC * NPOS * 2);          // 4.2 MB
    f16* partial = (f16*)alloc((size_t)NB * 4 * NPOS * IC * 2);  // 33.6 MB (persistent)

    k_prep_w<<<128, 256, 0, stream>>>(gw, tw, pw, Ww, wAll, Wc);
    k_proj<<<dim3(64, 8), 384, 0, stream>>>(x, wAll, gb, tb, pb, th, ph, gT);

    for (int b0 = 0; b0 < NB; b0 += 4) {
        k_gemm1<<<4096, 256, 0, stream>>>(th, ph, Ep, lmax, lsum, b0);
        k_prep<<<dim3(16, 4), 256, 0, stream>>>(lmax, lsum, gT, sca, gs, b0);
        k_gemm2<<<512, 256, 0, stream>>>(Ep, sca, gs, partial, b0);
    }
    k_conv<<<dim3(512), 256, 0, stream>>>(x, Wc, Wb, partial, out);
}